// Round 15
// baseline (879.362 us; speedup 1.0000x reference)
//
#include <hip/hip_runtime.h>

// ---------------------------------------------------------------------------
// SpatialAttention, N=8192, D=H=512, GAMMA=0.5
//   S = exp(maskR ? -inf : QrKr^T/sqrt(H)) + 0.5*exp(maskF ? -inf : QfKf^T/sqrt(H))
//   attn = S / rowsum(S);  cntx = attn @ (x Wv + bv)
// d_out = [cntx (N*D f32) | attn (N*N f32)]
//
// R15: packmask DELETED. Analysis: each bitfield word was consumed by
// exactly one scores2 block (no cross-block reuse), so the bitpack pass was
// a pure serialization cost (~100 us + 32 MB extra traffic). scores2's
// epilogue now reads the raw masks directly (64B-segment coalesced, 128
// independent loads/thread, overlapped with the co-resident block's K-loop).
// ---------------------------------------------------------------------------

#define K_N 8192
#define K_D 512

typedef float  f32x4 __attribute__((ext_vector_type(4)));
typedef _Float16 f16x8 __attribute__((ext_vector_type(8)));
typedef unsigned short u16;
typedef unsigned int u32;

__device__ __forceinline__ u16 f2h(float f) {
  _Float16 h = (_Float16)f;
  return __builtin_bit_cast(u16, h);
}
__device__ __forceinline__ float h2f(u16 b) {
  return (float)__builtin_bit_cast(_Float16, b);
}

__device__ __forceinline__ void gload_lds16(const void* g, void* l) {
  __builtin_amdgcn_global_load_lds(
      (const __attribute__((address_space(1))) void*)g,
      (__attribute__((address_space(3))) void*)l, 16, 0, 0);
}

__device__ __forceinline__ void nt_store4(float* p, f32x4 v) {
  __builtin_nontemporal_store(v, (f32x4*)p);
}

// ---------------------------------------------------------------------------
// Mask dtype detector (1-byte bool vs 4-byte int/float).
// ---------------------------------------------------------------------------
__global__ void k_detect(const unsigned char* __restrict__ m, int* __restrict__ flag) {
  __shared__ int any;
  if (threadIdx.x == 0) any = 0;
  __syncthreads();
  int local = 0;
  for (int i = threadIdx.x; i < 65536; i += 256)
    local |= m[4 * i + 1];
  if (local) atomicOr(&any, 1);
  __syncthreads();
  if (threadIdx.x == 0) *flag = any ? 1 : 0;
}

__device__ __forceinline__ bool mask_at(const void* mask, int mode, size_t idx) {
  if (mode) return ((const unsigned char*)mask)[idx] != 0;
  return ((const int*)mask)[idx] != 0;
}

// ---------------------------------------------------------------------------
__global__ void k_cvt_x(const float* __restrict__ x, u16* __restrict__ xh) {
  int i = blockIdx.x * 256 + threadIdx.x;
  float4 v = ((const float4*)x)[i];
  ushort4 o;
  o.x = f2h(v.x); o.y = f2h(v.y); o.z = f2h(v.z); o.w = f2h(v.w);
  ((ushort4*)xh)[i] = o;
}

__global__ void k_zero(float* __restrict__ p) {
  size_t i = (size_t)blockIdx.x * 256 + threadIdx.x;
  ((float4*)p)[i] = make_float4(0.f, 0.f, 0.f, 0.f);
}

template <int IN_F32>
__global__ void k_transpose(const void* __restrict__ in, u16* __restrict__ out,
                            int R, int C) {
  __shared__ u16 sm[64][65];
  int c0 = blockIdx.x * 64, r0 = blockIdx.y * 64;
#pragma unroll
  for (int e = 0; e < 16; e++) {
    int idx = e * 256 + threadIdx.x;
    int i = idx >> 6, j = idx & 63;
    u16 h;
    if (IN_F32) h = f2h(((const float*)in)[(size_t)(r0 + i) * C + c0 + j]);
    else        h = ((const u16*)in)[(size_t)(r0 + i) * C + c0 + j];
    sm[i][j] = h;
  }
  __syncthreads();
#pragma unroll
  for (int e = 0; e < 16; e++) {
    int idx = e * 256 + threadIdx.x;
    int j = idx >> 6, i = idx & 63;
    out[(size_t)(c0 + j) * R + r0 + i] = sm[i][j];
  }
}

// ---------------------------------------------------------------------------
// Reg-staged 4-wave GEMM core: C(128x128) += A(128xK)*Bt^T
// ---------------------------------------------------------------------------
template <int A_F32>
__device__ __forceinline__ void gemm_core(const void* __restrict__ Ap, int lda,
                                          const u16* __restrict__ Bt, int ldb,
                                          int rowBase, int colBase, int K,
                                          u16* sA, u16* sB, f32x4 (&acc)[4][4]) {
  const int tid   = threadIdx.x;
  const int lane  = tid & 63;
  const int waveM = tid >> 7;
  const int waveN = (tid >> 6) & 1;
  const int lrow  = lane & 15;
  const int lk    = lane >> 4;

  for (int k0 = 0; k0 < K; k0 += 64) {
    __syncthreads();
#pragma unroll
    for (int g = 0; g < 4; g++) {
      int cid = g * 256 + tid;
      int row = cid >> 3;
      int pk  = cid & 7;
      int k16 = pk ^ (row & 7);
      if (A_F32) {
        const float* s = (const float*)Ap + (size_t)(rowBase + row) * lda + k0 + k16 * 8;
        float4 v0 = *(const float4*)s;
        float4 v1 = *(const float4*)(s + 4);
        ushort4 h0, h1;
        h0.x = f2h(v0.x); h0.y = f2h(v0.y); h0.z = f2h(v0.z); h0.w = f2h(v0.w);
        h1.x = f2h(v1.x); h1.y = f2h(v1.y); h1.z = f2h(v1.z); h1.w = f2h(v1.w);
        *(ushort4*)&sA[cid * 8]     = h0;
        *(ushort4*)&sA[cid * 8 + 4] = h1;
      } else {
        uint4 v = *(const uint4*)((const u16*)Ap + (size_t)(rowBase + row) * lda + k0 + k16 * 8);
        *(uint4*)&sA[cid * 8] = v;
      }
      uint4 w = *(const uint4*)(Bt + (size_t)(colBase + row) * ldb + k0 + k16 * 8);
      *(uint4*)&sB[cid * 8] = w;
    }
    __syncthreads();
#pragma unroll
    for (int kk = 0; kk < 2; kk++) {
      f16x8 af[4], bfv[4];
      int k16 = kk * 4 + lk;
#pragma unroll
      for (int mb = 0; mb < 4; mb++) {
        int r = waveM * 64 + mb * 16 + lrow;
        af[mb] = *(const f16x8*)&sA[r * 64 + ((k16 ^ (r & 7)) << 3)];
      }
#pragma unroll
      for (int nb = 0; nb < 4; nb++) {
        int c = waveN * 64 + nb * 16 + lrow;
        bfv[nb] = *(const f16x8*)&sB[c * 64 + ((k16 ^ (c & 7)) << 3)];
      }
#pragma unroll
      for (int mb = 0; mb < 4; mb++)
#pragma unroll
        for (int nb = 0; nb < 4; nb++)
          acc[mb][nb] = __builtin_amdgcn_mfma_f32_16x16x32_f16(af[mb], bfv[nb], acc[mb][nb], 0, 0, 0);
    }
  }
}

// ---------------------------------------------------------------------------
// Projections: z=0..3 -> Q_r,K_r,Q_f,K_f; z=4 -> V=x@Wv+bv (all fp16)
// ---------------------------------------------------------------------------
__global__ __launch_bounds__(256) void k_proj(const u16* __restrict__ xh,
                                              const u16* __restrict__ wt,
                                              u16* __restrict__ qr, u16* __restrict__ kr,
                                              u16* __restrict__ qf, u16* __restrict__ kf,
                                              u16* __restrict__ vh,
                                              const float* __restrict__ bv) {
  __shared__ u16 sA[128 * 64], sB[128 * 64];
  f32x4 acc[4][4] = {};
  const int z = blockIdx.z;
  const int rowBase = blockIdx.y * 128, colBase = blockIdx.x * 128;
  gemm_core<0>(xh, K_D, wt + (size_t)z * 262144, K_D, rowBase, colBase, K_D, sA, sB, acc);

  u16* out = (z == 0) ? qr : (z == 1) ? kr : (z == 2) ? qf : (z == 3) ? kf : vh;
  const int lane = threadIdx.x & 63;
  const int waveM = threadIdx.x >> 7, waveN = (threadIdx.x >> 6) & 1;
  const int lrow = lane & 15, lk = lane >> 4;
#pragma unroll
  for (int mb = 0; mb < 4; mb++)
#pragma unroll
    for (int nb = 0; nb < 4; nb++)
#pragma unroll
      for (int r = 0; r < 4; r++) {
        int grow = rowBase + waveM * 64 + mb * 16 + lk * 4 + r;
        int gcol = colBase + waveN * 64 + nb * 16 + lrow;
        float v = acc[mb][nb][r];
        if (z == 4) v += bv[gcol];
        out[(size_t)grow * K_D + gcol] = f2h(v);
      }
}

// ---------------------------------------------------------------------------
// Main scores: 4 waves (256 thr), wave = 64x64, 64 KB dbuf, sequential R/F
// K-loops with cross-boundary prefetch, XCD swizzle, launch_bounds(256,2)
// (dual accumulators need ~190 VGPR -> 2 blocks/CU register limit).
// R15: epilogue reads RAW masks directly (packmask kernel deleted).
// ---------------------------------------------------------------------------
__global__ __launch_bounds__(256, 2) void k_scores2(
    const u16* __restrict__ qr, const u16* __restrict__ kr,
    const u16* __restrict__ qf, const u16* __restrict__ kf,
    const void* __restrict__ mR, const void* __restrict__ mF,
    const int* __restrict__ flag,
    u16* __restrict__ outp, float* __restrict__ partial) {

  __shared__ u16 s[2][2][8192];   // [dbuf][Q,K][128x64] = 64 KiB

  const int tid = threadIdx.x;
  const int lane = tid & 63, wid = tid >> 6;

  int b = blockIdx.x + (blockIdx.y << 6);
  int xcd = b & 7, j = b >> 3;            // j in [0,512)
  const int by = xcd * 8 + (j & 7);
  const int bx = j >> 3;
  const int rowBase = by * 128, colBase = bx * 128;

  const u16* qrB = qr + (size_t)rowBase * K_D;
  const u16* krB = kr + (size_t)colBase * K_D;
  const u16* qfB = qf + (size_t)rowBase * K_D;
  const u16* kfB = kf + (size_t)colBase * K_D;

  f32x4 accR[4][4] = {}, accF[4][4] = {};

  auto STAGE = [&](int buf, const u16* qb, const u16* kb, int k0) {
#pragma unroll
    for (int jj = 0; jj < 4; ++jj) {
      int cid = jj * 256 + tid;           // 16B chunk id, 0..1023
      int row = cid >> 3;
      int k16 = (cid & 7) ^ (row & 7);    // swizzled source -> linear LDS
      gload_lds16(qb + (size_t)row * K_D + k0 + k16 * 8,
                  &s[buf][0][(jj * 256 + wid * 64) * 8]);
      gload_lds16(kb + (size_t)row * K_D + k0 + k16 * 8,
                  &s[buf][1][(jj * 256 + wid * 64) * 8]);
    }
  };

  const int waveM = wid >> 1;         // 0..1 (64 rows)
  const int waveN = wid & 1;          // 0..1 (64 cols)
  const int lrow = lane & 15, lk = lane >> 4;

  auto COMPUTE = [&](f32x4 (&acc)[4][4], int cur) {
#pragma unroll
    for (int kk = 0; kk < 2; ++kk) {
      int k16 = kk * 4 + lk;
      f16x8 a[4], bb[4];
#pragma unroll
      for (int mb = 0; mb < 4; ++mb) {
        int r = waveM * 64 + mb * 16 + lrow;
        a[mb] = *(const f16x8*)&s[cur][0][r * 64 + ((k16 ^ (r & 7)) << 3)];
      }
#pragma unroll
      for (int nb = 0; nb < 4; ++nb) {
        int c = waveN * 64 + nb * 16 + lrow;
        bb[nb] = *(const f16x8*)&s[cur][1][c * 64 + ((k16 ^ (c & 7)) << 3)];
      }
#pragma unroll
      for (int mb = 0; mb < 4; ++mb)
#pragma unroll
        for (int nb = 0; nb < 4; ++nb)
          acc[mb][nb] = __builtin_amdgcn_mfma_f32_16x16x32_f16(a[mb], bb[nb], acc[mb][nb], 0, 0, 0);
    }
  };

  STAGE(0, qrB, krB, 0);
  __syncthreads();
  int cur = 0;
  for (int it = 0; it < 8; ++it) {        // real branch
    if (it < 7) STAGE(cur ^ 1, qrB, krB, (it + 1) * 64);
    else        STAGE(cur ^ 1, qfB, kfB, 0);
    COMPUTE(accR, cur);
    __syncthreads();
    cur ^= 1;
  }
  for (int it = 0; it < 8; ++it) {        // fake branch
    if (it < 7) STAGE(cur ^ 1, qfB, kfB, (it + 1) * 64);
    COMPUTE(accF, cur);
    __syncthreads();
    cur ^= 1;
  }

  // ---- epilogue: raw-mask exp, rowsum partials, coalesced fp16 store ----
  const float scale = 0.04419417382415922f;   // 1/sqrt(512)
  const int mode = *flag;
  u16* vt16 = (u16*)&s[0][0][0];              // [128][136] fp16 restage

#pragma unroll
  for (int mb = 0; mb < 4; ++mb)
#pragma unroll
    for (int rr = 0; rr < 4; ++rr) {
      int growl = waveM * 64 + mb * 16 + lk * 4 + rr;
      int grow = rowBase + growl;
      const size_t rbase = (size_t)grow * K_N + colBase + waveN * 64;
      float rs = 0.f;
#pragma unroll
      for (int nb = 0; nb < 4; ++nb) {
        int cc = nb * 16 + lrow;            // 0..63 within wave cols
        int gcoll = waveN * 64 + cc;
        bool m1 = mask_at(mR, mode, rbase + cc);
        bool m2 = mask_at(mF, mode, rbase + cc);
        float er = m1 ? 0.f : __expf(accR[mb][nb][rr] * scale);
        float ef = m2 ? 0.f : __expf(accF[mb][nb][rr] * scale);
        float v = er + 0.5f * ef;
        rs += v;
        vt16[growl * 136 + gcoll] = f2h(v);
      }
      rs += __shfl_xor(rs, 1, 64);
      rs += __shfl_xor(rs, 2, 64);
      rs += __shfl_xor(rs, 4, 64);
      rs += __shfl_xor(rs, 8, 64);
      if (lrow == 0)
        partial[(size_t)grow * 128 + bx * 2 + waveN] = rs;
    }
  __syncthreads();

#pragma unroll
  for (int jj = 0; jj < 8; ++jj) {
    int f = jj * 256 + tid;             // 16B unit in 128x128 fp16 tile
    int row = f >> 4, seg = f & 15;
    uint4 v = *(const uint4*)&vt16[row * 136 + seg * 8];
    *(uint4*)&outp[(size_t)(rowBase + row) * K_N + colBase + seg * 8] = v;
  }
}

// ---------------------------------------------------------------------------
// Fallback scores: 8-wave, 128 KB LDS, raw masks (partial stride 256).
// ---------------------------------------------------------------------------
__global__ __launch_bounds__(512, 2) void k_scores8(
    const u16* __restrict__ qr, const u16* __restrict__ kr,
    const u16* __restrict__ qf, const u16* __restrict__ kf,
    const void* __restrict__ mR, const void* __restrict__ mF,
    const int* __restrict__ flag,
    float* __restrict__ outp, float* __restrict__ partial) {

  __shared__ u16 s[2][4][8192];

  const int tid = threadIdx.x;
  const int lane = tid & 63, wid = tid >> 6;
  const int bx = blockIdx.x, by = blockIdx.y;
  const int rowBase = by * 128, colBase = bx * 128;

  const u16* base0 = qr + (size_t)rowBase * K_D;
  const u16* base1 = kr + (size_t)colBase * K_D;
  const u16* base2 = qf + (size_t)rowBase * K_D;
  const u16* base3 = kf + (size_t)colBase * K_D;

  f32x4 accR[4][2] = {}, accF[4][2] = {};

  auto STAGE = [&](int b, int k0) {
    const u16* bases[4] = {base0, base1, base2, base3};
#pragma unroll
    for (int t = 0; t < 4; ++t)
#pragma unroll
      for (int j = 0; j < 2; ++j) {
        int cid = j * 512 + tid;
        int row = cid >> 3;
        int k16 = (cid & 7) ^ (row & 7);
        gload_lds16(bases[t] + (size_t)row * K_D + k0 + k16 * 8,
                    &s[b][t][(j * 512 + wid * 64) * 8]);
      }
  };

  STAGE(0, 0);
  __syncthreads();

  const int waveM = wid >> 2, waveN = wid & 3;
  const int lrow = lane & 15, lk = lane >> 4;

  int cur = 0;
  for (int it = 0; it < 8; ++it) {
    if (it < 7) STAGE(cur ^ 1, (it + 1) * 64);
#pragma unroll
    for (int kk = 0; kk < 2; ++kk) {
      int k16 = kk * 4 + lk;
      f16x8 aR[4], aF[4], bR[2], bF[2];
#pragma unroll
      for (int mb = 0; mb < 4; ++mb) {
        int r = waveM * 64 + mb * 16 + lrow;
        int off = r * 64 + ((k16 ^ (r & 7)) << 3);
        aR[mb] = *(const f16x8*)&s[cur][0][off];
        aF[mb] = *(const f16x8*)&s[cur][2][off];
      }
#pragma unroll
      for (int nb = 0; nb < 2; ++nb) {
        int c = waveN * 32 + nb * 16 + lrow;
        int off = c * 64 + ((k16 ^ (c & 7)) << 3);
        bR[nb] = *(const f16x8*)&s[cur][1][off];
        bF[nb] = *(const f16x8*)&s[cur][3][off];
      }
#pragma unroll
      for (int mb = 0; mb < 4; ++mb)
#pragma unroll
        for (int nb = 0; nb < 2; ++nb) {
          accR[mb][nb] = __builtin_amdgcn_mfma_f32_16x16x32_f16(aR[mb], bR[nb], accR[mb][nb], 0, 0, 0);
          accF[mb][nb] = __builtin_amdgcn_mfma_f32_16x16x32_f16(aF[mb], bF[nb], accF[mb][nb], 0, 0, 0);
        }
    }
    __syncthreads();
    cur ^= 1;
  }

  const float scale = 0.04419417382415922f;
  const int mode = *flag;
  float* vt32 = (float*)&s[0][0][0];

#pragma unroll
  for (int mb = 0; mb < 4; ++mb)
#pragma unroll
    for (int rr = 0; rr < 4; ++rr) {
      int growl = waveM * 64 + mb * 16 + lk * 4 + rr;
      int grow = rowBase + growl;
      float rs = 0.f;
#pragma unroll
      for (int nb = 0; nb < 2; ++nb) {
        int bitpos = nb * 16 + lrow;
        int gcoll = waveN * 32 + bitpos;
        size_t oi = (size_t)grow * K_N + colBase + gcoll;
        bool m1 = mask_at(mR, mode, oi);
        bool m2 = mask_at(mF, mode, oi);
        float er = m1 ? 0.f : __expf(accR[mb][nb][rr] * scale);
        float ef = m2 ? 0.f : __expf(accF[mb][nb][rr] * scale);
        float v = er + 0.5f * ef;
        rs += v;
        vt32[growl * 132 + gcoll] = v;
      }
      rs += __shfl_xor(rs, 1, 64);
      rs += __shfl_xor(rs, 2, 64);
      rs += __shfl_xor(rs, 4, 64);
      rs += __shfl_xor(rs, 8, 64);
      if (lrow == 0)
        partial[(size_t)grow * 256 + bx * 4 + waveN] = rs;
    }
  __syncthreads();

#pragma unroll
  for (int j = 0; j < 8; ++j) {
    int f = j * 512 + tid;
    int row = f >> 5, seg = f & 31;
    float4 v = *(const float4*)&vt32[row * 132 + seg * 4];
    *(float4*)&outp[(size_t)(rowBase + row) * K_N + colBase + seg * 4] = v;
  }
}

// ---------------------------------------------------------------------------
template <int STRIDE>
__global__ void k_rowsum(const float* __restrict__ partial, float* __restrict__ inv) {
  int r = blockIdx.x * 256 + threadIdx.x;
  const float4* p = (const float4*)(partial + (size_t)r * STRIDE);
  float s = 0.f;
#pragma unroll 8
  for (int j = 0; j < STRIDE / 4; j++) {
    float4 v = p[j];
    s += v.x + v.y + v.z + v.w;
  }
  inv[r] = 1.0f / s;
}

// fallback in-place fp32 norm
__global__ void k_norm_b(float* __restrict__ attn, const float* __restrict__ inv) {
  const size_t total = (size_t)K_N * K_N / 4;
  for (size_t i = (size_t)blockIdx.x * 256 + threadIdx.x; i < total;
       i += (size_t)gridDim.x * 256) {
    int row = (int)(i >> 11);
    float s = inv[row];
    float4 v = ((float4*)attn)[i];
    v.x *= s; v.y *= s; v.z *= s; v.w *= s;
    ((float4*)attn)[i] = v;
  }
}

// ---------------------------------------------------------------------------
// cntx: split-K, 4 blocks/CU, atomic accumulation into zeroed cntx,
// nontemporal attn stores. Block = (stripe 128 rows) x (ch 128 cols) x
// (ks K-range 2048); all 16 blocks of a stripe on one XCD.
// ---------------------------------------------------------------------------
__global__ __launch_bounds__(256, 4) void k_cntx6(
    const u16* __restrict__ sh, const u16* __restrict__ vT,
    const float* __restrict__ inv, float* __restrict__ cntx,
    float* __restrict__ attn) {
  __shared__ u16 sA[128 * 64], sB[128 * 64];
  f32x4 acc[4][4] = {};

  const int tid = threadIdx.x;
  int b = blockIdx.x + (blockIdx.y << 3);   // grid (8,128) -> b in [0,1024)
  int xcd = b & 7, j = b >> 3;              // j in [0,128)
  const int s  = xcd + 8 * (j >> 4);        // stripe 0..63
  const int u  = j & 15;
  const int ch = u >> 2;                    // col block 0..3
  const int ks = u & 3;                     // K split 0..3
  const int rowBase = s * 128, colBase = ch * 128;
  const int k0 = ks * 2048;

  gemm_core<0>(sh + (size_t)k0, K_N, vT + (size_t)k0, K_N,
               rowBase, colBase, 2048, sA, sB, acc);

  // atomic partial accumulation (inv applied per partial; sum distributes)
  const int lane = tid & 63;
  const int waveM = tid >> 7, waveN = (tid >> 6) & 1;
  const int lrow = lane & 15, lk = lane >> 4;
#pragma unroll
  for (int mb = 0; mb < 4; mb++)
#pragma unroll
    for (int rr = 0; rr < 4; rr++) {
      int grow = rowBase + waveM * 64 + mb * 16 + lk * 4 + rr;
      float iv = inv[grow];
#pragma unroll
      for (int nb = 0; nb < 4; nb++) {
        int gcol = colBase + waveN * 64 + nb * 16 + lrow;
        atomicAdd(&cntx[(size_t)grow * K_D + gcol], acc[mb][nb][rr] * iv);
      }
    }

  // attn normalize: rows [rowBase,+128), cols [ks*2048 + ch*512, +512)
  const int ac0 = ks * 2048 + ch * 512;
  const u16* src = sh + (size_t)rowBase * K_N + ac0;
  float* ad = attn + (size_t)rowBase * K_N + ac0;
  for (int i = tid; i < 128 * 64; i += 256) {   // 8-elem chunks
    int row = i >> 6, c8 = i & 63;
    float sc = inv[rowBase + row];
    uint4 v = *(const uint4*)&src[(size_t)row * K_N + c8 * 8];
    f32x4 o0, o1;
    o0.x = h2f(v.x & 0xFFFF) * sc; o0.y = h2f(v.x >> 16) * sc;
    o0.z = h2f(v.y & 0xFFFF) * sc; o0.w = h2f(v.y >> 16) * sc;
    o1.x = h2f(v.z & 0xFFFF) * sc; o1.y = h2f(v.z >> 16) * sc;
    o1.z = h2f(v.w & 0xFFFF) * sc; o1.w = h2f(v.w >> 16) * sc;
    float* d2 = ad + (size_t)row * K_N + c8 * 8;
    nt_store4(d2, o0);
    nt_store4(d2 + 4, o1);
  }
}

// ---------------------------------------------------------------------------
// Fallback cntx (reads fp32 attn), no attn emission.
// ---------------------------------------------------------------------------
__global__ __launch_bounds__(256) void k_cntx(const void* __restrict__ Ap,
                                              const u16* __restrict__ vT,
                                              const float* __restrict__ inv,
                                              float* __restrict__ out) {
  __shared__ u16 sA[128 * 64], sB[128 * 64];
  f32x4 acc[4][4] = {};
  int b = blockIdx.x + blockIdx.y * 4;
  int c = b & 7, jj = b >> 3;
  int xb = jj & 3, yb = c + 8 * (jj >> 2);
  const int rowBase = yb * 128, colBase = xb * 128;
  gemm_core<1>(Ap, K_N, vT, K_N, rowBase, colBase, K_N, sA, sB, acc);

  const int lane = threadIdx.x & 63;
  const int waveM = threadIdx.x >> 7, waveN = (threadIdx.x >> 6) & 1;
  const int lrow = lane & 15, lk = lane >> 4;
#pragma unroll
  for (int mb = 0; mb < 4; mb++)
#pragma unroll
    for (int r = 0; r < 4; r++) {
      int grow = rowBase + waveM * 64 + mb * 16 + lk * 4 + r;
      float iv = inv[grow];
#pragma unroll
      for (int nb = 0; nb < 4; nb++) {
        int gcol = colBase + waveN * 64 + nb * 16 + lrow;
        out[(size_t)grow * K_D + gcol] = acc[mb][nb][r] * iv;
      }
    }
}

// ---------------------------------------------------------------------------
extern "C" void kernel_launch(void* const* d_in, const int* in_sizes, int n_in,
                              void* d_out, int out_size, void* d_ws, size_t ws_size,
                              hipStream_t stream) {
  const float* x   = (const float*)d_in[0];
  const void*  mR  = d_in[1];
  const void*  mF  = d_in[2];
  const float* Wv  = (const float*)d_in[7];
  const float* bv  = (const float*)d_in[8];

  const size_t ND = (size_t)K_N * K_D;
  u16* xh = (u16*)d_ws;
  u16* qr = xh + ND;
  u16* kr = qr + ND;
  u16* qf = kr + ND;
  u16* kf = qf + ND;
  u16* vh = kf + ND;
  u16* vT = vh + ND;
  u16* wt = vT + ND;
  u16* sh = wt + 5 * 262144;               // fp16 scores scratch, 128 MB
  // flag lives after sh (or in cntx region if no sh)
  const size_t need_sh = (size_t)((char*)sh - (char*)d_ws) + (size_t)K_N * K_N * 2 + 64;
  const bool have_sh = ws_size >= need_sh;

  float* cntx = (float*)d_out;
  float* attn = cntx + ND;
  float* partial = (float*)d_ws;                 // overlays xh (dead after proj)
  float* inv     = (float*)qr;                   // overlays qr (dead after scores)
  int* flag = have_sh ? (int*)(sh + (size_t)K_N * K_N) : (int*)cntx;

  k_detect<<<1, 256, 0, stream>>>((const unsigned char*)mR, flag);

  k_cvt_x<<<4096, 256, 0, stream>>>(x, xh);
  k_transpose<1><<<dim3(8, 8), 256, 0, stream>>>((const void*)d_in[3], wt + 0 * 262144, 512, 512);
  k_transpose<1><<<dim3(8, 8), 256, 0, stream>>>((const void*)d_in[4], wt + 1 * 262144, 512, 512);
  k_transpose<1><<<dim3(8, 8), 256, 0, stream>>>((const void*)d_in[5], wt + 2 * 262144, 512, 512);
  k_transpose<1><<<dim3(8, 8), 256, 0, stream>>>((const void*)d_in[6], wt + 3 * 262144, 512, 512);
  k_transpose<1><<<dim3(8, 8), 256, 0, stream>>>(Wv,  wt + 4 * 262144, 512, 512);

  k_proj<<<dim3(4, 64, 5), 256, 0, stream>>>(xh, wt, qr, kr, qf, kf, vh, bv);
  k_transpose<0><<<dim3(8, 128), 256, 0, stream>>>(vh, vT, K_N, K_D);

  if (have_sh) {
    k_scores2<<<dim3(64, 64), 256, 0, stream>>>(qr, kr, qf, kf, mR, mF, flag, sh, partial);
    k_rowsum<128><<<32, 256, 0, stream>>>(partial, inv);
    k_zero<<<4096, 256, 0, stream>>>(cntx);
    k_cntx6<<<dim3(8, 128), 256, 0, stream>>>(sh, vT, inv, cntx, attn);
  } else {
    k_scores8<<<dim3(64, 64), 512, 0, stream>>>(qr, kr, qf, kf, mR, mF, flag, attn, partial);
    k_rowsum<256><<<32, 256, 0, stream>>>(partial, inv);
    k_cntx<<<dim3(4, 64), 256, 0, stream>>>(attn, vT, inv, cntx);
    k_norm_b<<<8192, 256, 0, stream>>>(attn, inv);
  }
}

// Round 16
// 580.786 us; speedup vs baseline: 1.5141x; 1.5141x over previous
//
#include <hip/hip_runtime.h>

// ---------------------------------------------------------------------------
// SpatialAttention, N=8192, D=H=512, GAMMA=0.5
//   S = exp(maskR ? -inf : QrKr^T/sqrt(H)) + 0.5*exp(maskF ? -inf : QfKf^T/sqrt(H))
//   attn = S / rowsum(S);  cntx = attn @ (x Wv + bv)
// d_out = [cntx (N*D f32) | attn (N*N f32)]
//
// R16 = REVERT to R14 known-good (580 us). R15's inline raw-mask read put
// 512 MB of scattered latency-exposed loads in scores2's tail (+415 us);
// the bitfield prepass converts that to a 100 us streaming pass. Keep it.
// ---------------------------------------------------------------------------

#define K_N 8192
#define K_D 512

typedef float  f32x4 __attribute__((ext_vector_type(4)));
typedef _Float16 f16x8 __attribute__((ext_vector_type(8)));
typedef unsigned short u16;
typedef unsigned int u32;

__device__ __forceinline__ u16 f2h(float f) {
  _Float16 h = (_Float16)f;
  return __builtin_bit_cast(u16, h);
}
__device__ __forceinline__ float h2f(u16 b) {
  return (float)__builtin_bit_cast(_Float16, b);
}

__device__ __forceinline__ void gload_lds16(const void* g, void* l) {
  __builtin_amdgcn_global_load_lds(
      (const __attribute__((address_space(1))) void*)g,
      (__attribute__((address_space(3))) void*)l, 16, 0, 0);
}

__device__ __forceinline__ void nt_store4(float* p, f32x4 v) {
  __builtin_nontemporal_store(v, (f32x4*)p);
}

// ---------------------------------------------------------------------------
// Mask dtype detector (1-byte bool vs 4-byte int/float).
// ---------------------------------------------------------------------------
__global__ void k_detect(const unsigned char* __restrict__ m, int* __restrict__ flag) {
  __shared__ int any;
  if (threadIdx.x == 0) any = 0;
  __syncthreads();
  int local = 0;
  for (int i = threadIdx.x; i < 65536; i += 256)
    local |= m[4 * i + 1];
  if (local) atomicOr(&any, 1);
  __syncthreads();
  if (threadIdx.x == 0) *flag = any ? 1 : 0;
}

__device__ __forceinline__ bool mask_at(const void* mask, int mode, size_t idx) {
  if (mode) return ((const unsigned char*)mask)[idx] != 0;
  return ((const int*)mask)[idx] != 0;
}

// ---------------------------------------------------------------------------
// pack 32 mask elements starting at (r, 32c) into one u32 (bit k = elem!=0)
// ---------------------------------------------------------------------------
__device__ __forceinline__ u32 pack_word(const void* m, int mode, int r, int c) {
  u32 out = 0;
  if (mode) {  // 1-byte elements: 32 B contiguous
    const uint4* p = (const uint4*)((const unsigned char*)m + (size_t)r * K_N + c * 32);
    uint4 a = p[0], b = p[1];
    u32 ws[8] = {a.x, a.y, a.z, a.w, b.x, b.y, b.z, b.w};
#pragma unroll
    for (int i = 0; i < 8; i++) {
      u32 v = ws[i];
      v |= v >> 4; v |= v >> 2; v |= v >> 1;
      v &= 0x01010101u;
      out |= (v & 1u) << (4 * i);
      out |= ((v >> 8) & 1u) << (4 * i + 1);
      out |= ((v >> 16) & 1u) << (4 * i + 2);
      out |= ((v >> 24) & 1u) << (4 * i + 3);
    }
  } else {     // 4-byte elements: 128 B contiguous
    const uint4* p = (const uint4*)((const int*)m + (size_t)r * K_N + c * 32);
#pragma unroll
    for (int i = 0; i < 8; i++) {
      uint4 v = p[i];
      out |= (v.x ? 1u : 0u) << (4 * i);
      out |= (v.y ? 1u : 0u) << (4 * i + 1);
      out |= (v.z ? 1u : 0u) << (4 * i + 2);
      out |= (v.w ? 1u : 0u) << (4 * i + 3);
    }
  }
  return out;
}

// ---------------------------------------------------------------------------
// packmask: LDS-transposed tiles (R11). Read input-major, write output-major.
// ---------------------------------------------------------------------------
__global__ __launch_bounds__(256) void k_packmask2(
    const void* __restrict__ mR, const void* __restrict__ mF,
    const int* __restrict__ flag,
    u32* __restrict__ bR, u32* __restrict__ bF) {
  __shared__ u32 sm[32][129];
  const int mode = *flag;
  const int tid = threadIdx.x;
  const int r0 = blockIdx.x * 128;
  const int c0 = blockIdx.y * 32;

#pragma unroll
  for (int t = 0; t < 2; ++t) {
    const void* m = t ? mF : mR;
    u32* dst = t ? bF : bR;
    if (t) __syncthreads();
#pragma unroll 4
    for (int i = 0; i < 16; ++i) {
      int idx = i * 256 + tid;
      int r = idx >> 5, c = idx & 31;
      sm[c][r] = pack_word(m, mode, r0 + r, c0 + c);
    }
    __syncthreads();
#pragma unroll 4
    for (int i = 0; i < 16; ++i) {
      int idx = i * 256 + tid;
      int c = idx >> 7, r = idx & 127;
      dst[(size_t)(c0 + c) * K_N + r0 + r] = sm[c][r];
    }
  }
}

// ---------------------------------------------------------------------------
__global__ void k_cvt_x(const float* __restrict__ x, u16* __restrict__ xh) {
  int i = blockIdx.x * 256 + threadIdx.x;
  float4 v = ((const float4*)x)[i];
  ushort4 o;
  o.x = f2h(v.x); o.y = f2h(v.y); o.z = f2h(v.z); o.w = f2h(v.w);
  ((ushort4*)xh)[i] = o;
}

__global__ void k_zero(float* __restrict__ p) {
  size_t i = (size_t)blockIdx.x * 256 + threadIdx.x;
  ((float4*)p)[i] = make_float4(0.f, 0.f, 0.f, 0.f);
}

template <int IN_F32>
__global__ void k_transpose(const void* __restrict__ in, u16* __restrict__ out,
                            int R, int C) {
  __shared__ u16 sm[64][65];
  int c0 = blockIdx.x * 64, r0 = blockIdx.y * 64;
#pragma unroll
  for (int e = 0; e < 16; e++) {
    int idx = e * 256 + threadIdx.x;
    int i = idx >> 6, j = idx & 63;
    u16 h;
    if (IN_F32) h = f2h(((const float*)in)[(size_t)(r0 + i) * C + c0 + j]);
    else        h = ((const u16*)in)[(size_t)(r0 + i) * C + c0 + j];
    sm[i][j] = h;
  }
  __syncthreads();
#pragma unroll
  for (int e = 0; e < 16; e++) {
    int idx = e * 256 + threadIdx.x;
    int j = idx >> 6, i = idx & 63;
    out[(size_t)(c0 + j) * R + r0 + i] = sm[i][j];
  }
}

// ---------------------------------------------------------------------------
// Reg-staged 4-wave GEMM core: C(128x128) += A(128xK)*Bt^T
// ---------------------------------------------------------------------------
template <int A_F32>
__device__ __forceinline__ void gemm_core(const void* __restrict__ Ap, int lda,
                                          const u16* __restrict__ Bt, int ldb,
                                          int rowBase, int colBase, int K,
                                          u16* sA, u16* sB, f32x4 (&acc)[4][4]) {
  const int tid   = threadIdx.x;
  const int lane  = tid & 63;
  const int waveM = tid >> 7;
  const int waveN = (tid >> 6) & 1;
  const int lrow  = lane & 15;
  const int lk    = lane >> 4;

  for (int k0 = 0; k0 < K; k0 += 64) {
    __syncthreads();
#pragma unroll
    for (int g = 0; g < 4; g++) {
      int cid = g * 256 + tid;
      int row = cid >> 3;
      int pk  = cid & 7;
      int k16 = pk ^ (row & 7);
      if (A_F32) {
        const float* s = (const float*)Ap + (size_t)(rowBase + row) * lda + k0 + k16 * 8;
        float4 v0 = *(const float4*)s;
        float4 v1 = *(const float4*)(s + 4);
        ushort4 h0, h1;
        h0.x = f2h(v0.x); h0.y = f2h(v0.y); h0.z = f2h(v0.z); h0.w = f2h(v0.w);
        h1.x = f2h(v1.x); h1.y = f2h(v1.y); h1.z = f2h(v1.z); h1.w = f2h(v1.w);
        *(ushort4*)&sA[cid * 8]     = h0;
        *(ushort4*)&sA[cid * 8 + 4] = h1;
      } else {
        uint4 v = *(const uint4*)((const u16*)Ap + (size_t)(rowBase + row) * lda + k0 + k16 * 8);
        *(uint4*)&sA[cid * 8] = v;
      }
      uint4 w = *(const uint4*)(Bt + (size_t)(colBase + row) * ldb + k0 + k16 * 8);
      *(uint4*)&sB[cid * 8] = w;
    }
    __syncthreads();
#pragma unroll
    for (int kk = 0; kk < 2; kk++) {
      f16x8 af[4], bfv[4];
      int k16 = kk * 4 + lk;
#pragma unroll
      for (int mb = 0; mb < 4; mb++) {
        int r = waveM * 64 + mb * 16 + lrow;
        af[mb] = *(const f16x8*)&sA[r * 64 + ((k16 ^ (r & 7)) << 3)];
      }
#pragma unroll
      for (int nb = 0; nb < 4; nb++) {
        int c = waveN * 64 + nb * 16 + lrow;
        bfv[nb] = *(const f16x8*)&sB[c * 64 + ((k16 ^ (c & 7)) << 3)];
      }
#pragma unroll
      for (int mb = 0; mb < 4; mb++)
#pragma unroll
        for (int nb = 0; nb < 4; nb++)
          acc[mb][nb] = __builtin_amdgcn_mfma_f32_16x16x32_f16(af[mb], bfv[nb], acc[mb][nb], 0, 0, 0);
    }
  }
}

// ---------------------------------------------------------------------------
// Projections: z=0..3 -> Q_r,K_r,Q_f,K_f; z=4 -> V=x@Wv+bv (all fp16)
// ---------------------------------------------------------------------------
__global__ __launch_bounds__(256) void k_proj(const u16* __restrict__ xh,
                                              const u16* __restrict__ wt,
                                              u16* __restrict__ qr, u16* __restrict__ kr,
                                              u16* __restrict__ qf, u16* __restrict__ kf,
                                              u16* __restrict__ vh,
                                              const float* __restrict__ bv) {
  __shared__ u16 sA[128 * 64], sB[128 * 64];
  f32x4 acc[4][4] = {};
  const int z = blockIdx.z;
  const int rowBase = blockIdx.y * 128, colBase = blockIdx.x * 128;
  gemm_core<0>(xh, K_D, wt + (size_t)z * 262144, K_D, rowBase, colBase, K_D, sA, sB, acc);

  u16* out = (z == 0) ? qr : (z == 1) ? kr : (z == 2) ? qf : (z == 3) ? kf : vh;
  const int lane = threadIdx.x & 63;
  const int waveM = threadIdx.x >> 7, waveN = (threadIdx.x >> 6) & 1;
  const int lrow = lane & 15, lk = lane >> 4;
#pragma unroll
  for (int mb = 0; mb < 4; mb++)
#pragma unroll
    for (int nb = 0; nb < 4; nb++)
#pragma unroll
      for (int r = 0; r < 4; r++) {
        int grow = rowBase + waveM * 64 + mb * 16 + lk * 4 + r;
        int gcol = colBase + waveN * 64 + nb * 16 + lrow;
        float v = acc[mb][nb][r];
        if (z == 4) v += bv[gcol];
        out[(size_t)grow * K_D + gcol] = f2h(v);
      }
}

// ---------------------------------------------------------------------------
// Main scores: 4 waves (256 thr), wave = 64x64, 64 KB dbuf, sequential R/F
// K-loops with cross-boundary prefetch, XCD swizzle, dual-bit-word epilogue,
// partial stride 128. launch_bounds(256,2): dual accumulators ~190 VGPR ->
// 2 blocks/CU register limit (R13 proved (256,4) spills catastrophically).
// ---------------------------------------------------------------------------
__global__ __launch_bounds__(256, 2) void k_scores2(
    const u16* __restrict__ qr, const u16* __restrict__ kr,
    const u16* __restrict__ qf, const u16* __restrict__ kf,
    const u32* __restrict__ bitR, const u32* __restrict__ bitF,
    u16* __restrict__ outp, float* __restrict__ partial) {

  __shared__ u16 s[2][2][8192];   // [dbuf][Q,K][128x64] = 64 KiB

  const int tid = threadIdx.x;
  const int lane = tid & 63, wid = tid >> 6;

  int b = blockIdx.x + (blockIdx.y << 6);
  int xcd = b & 7, j = b >> 3;            // j in [0,512)
  const int by = xcd * 8 + (j & 7);
  const int bx = j >> 3;
  const int rowBase = by * 128, colBase = bx * 128;

  const u16* qrB = qr + (size_t)rowBase * K_D;
  const u16* krB = kr + (size_t)colBase * K_D;
  const u16* qfB = qf + (size_t)rowBase * K_D;
  const u16* kfB = kf + (size_t)colBase * K_D;

  f32x4 accR[4][4] = {}, accF[4][4] = {};

  auto STAGE = [&](int buf, const u16* qb, const u16* kb, int k0) {
#pragma unroll
    for (int jj = 0; jj < 4; ++jj) {
      int cid = jj * 256 + tid;           // 16B chunk id, 0..1023
      int row = cid >> 3;
      int k16 = (cid & 7) ^ (row & 7);    // swizzled source -> linear LDS
      gload_lds16(qb + (size_t)row * K_D + k0 + k16 * 8,
                  &s[buf][0][(jj * 256 + wid * 64) * 8]);
      gload_lds16(kb + (size_t)row * K_D + k0 + k16 * 8,
                  &s[buf][1][(jj * 256 + wid * 64) * 8]);
    }
  };

  const int waveM = wid >> 1;         // 0..1 (64 rows)
  const int waveN = wid & 1;          // 0..1 (64 cols)
  const int lrow = lane & 15, lk = lane >> 4;

  auto COMPUTE = [&](f32x4 (&acc)[4][4], int cur) {
#pragma unroll
    for (int kk = 0; kk < 2; ++kk) {
      int k16 = kk * 4 + lk;
      f16x8 a[4], bb[4];
#pragma unroll
      for (int mb = 0; mb < 4; ++mb) {
        int r = waveM * 64 + mb * 16 + lrow;
        a[mb] = *(const f16x8*)&s[cur][0][r * 64 + ((k16 ^ (r & 7)) << 3)];
      }
#pragma unroll
      for (int nb = 0; nb < 4; ++nb) {
        int c = waveN * 64 + nb * 16 + lrow;
        bb[nb] = *(const f16x8*)&s[cur][1][c * 64 + ((k16 ^ (c & 7)) << 3)];
      }
#pragma unroll
      for (int mb = 0; mb < 4; ++mb)
#pragma unroll
        for (int nb = 0; nb < 4; ++nb)
          acc[mb][nb] = __builtin_amdgcn_mfma_f32_16x16x32_f16(a[mb], bb[nb], acc[mb][nb], 0, 0, 0);
    }
  };

  STAGE(0, qrB, krB, 0);
  __syncthreads();
  int cur = 0;
  for (int it = 0; it < 8; ++it) {        // real branch
    if (it < 7) STAGE(cur ^ 1, qrB, krB, (it + 1) * 64);
    else        STAGE(cur ^ 1, qfB, kfB, 0);
    COMPUTE(accR, cur);
    __syncthreads();
    cur ^= 1;
  }
  for (int it = 0; it < 8; ++it) {        // fake branch
    if (it < 7) STAGE(cur ^ 1, qfB, kfB, (it + 1) * 64);
    COMPUTE(accF, cur);
    __syncthreads();
    cur ^= 1;
  }

  // ---- epilogue: masked exp, rowsum partials, coalesced fp16 store ----
  const float scale = 0.04419417382415922f;   // 1/sqrt(512)
  u16* vt16 = (u16*)&s[0][0][0];              // [128][136] fp16 restage

#pragma unroll
  for (int mb = 0; mb < 4; ++mb)
#pragma unroll
    for (int rr = 0; rr < 4; ++rr) {
      int growl = waveM * 64 + mb * 16 + lk * 4 + rr;
      int grow = rowBase + growl;
      u32 wR0 = bitR[(size_t)(bx * 4 + waveN * 2 + 0) * K_N + grow];
      u32 wR1 = bitR[(size_t)(bx * 4 + waveN * 2 + 1) * K_N + grow];
      u32 wF0 = bitF[(size_t)(bx * 4 + waveN * 2 + 0) * K_N + grow];
      u32 wF1 = bitF[(size_t)(bx * 4 + waveN * 2 + 1) * K_N + grow];
      float rs = 0.f;
#pragma unroll
      for (int nb = 0; nb < 4; ++nb) {
        int cc = nb * 16 + lrow;            // 0..63 within wave cols
        int gcoll = waveN * 64 + cc;
        u32 wR = (cc >> 5) ? wR1 : wR0;
        u32 wF = (cc >> 5) ? wF1 : wF0;
        int bitpos = cc & 31;
        bool m1 = (wR >> bitpos) & 1u;
        bool m2 = (wF >> bitpos) & 1u;
        float er = m1 ? 0.f : __expf(accR[mb][nb][rr] * scale);
        float ef = m2 ? 0.f : __expf(accF[mb][nb][rr] * scale);
        float v = er + 0.5f * ef;
        rs += v;
        vt16[growl * 136 + gcoll] = f2h(v);
      }
      rs += __shfl_xor(rs, 1, 64);
      rs += __shfl_xor(rs, 2, 64);
      rs += __shfl_xor(rs, 4, 64);
      rs += __shfl_xor(rs, 8, 64);
      if (lrow == 0)
        partial[(size_t)grow * 128 + bx * 2 + waveN] = rs;
    }
  __syncthreads();

#pragma unroll
  for (int jj = 0; jj < 8; ++jj) {
    int f = jj * 256 + tid;             // 16B unit in 128x128 fp16 tile
    int row = f >> 4, seg = f & 15;
    uint4 v = *(const uint4*)&vt16[row * 136 + seg * 8];
    *(uint4*)&outp[(size_t)(rowBase + row) * K_N + colBase + seg * 8] = v;
  }
}

// ---------------------------------------------------------------------------
// Fallback scores: 8-wave, 128 KB LDS, raw masks or bits (partial stride 256).
// ---------------------------------------------------------------------------
template <int F16OUT, int USEBITS>
__global__ __launch_bounds__(512, 2) void k_scores8(
    const u16* __restrict__ qr, const u16* __restrict__ kr,
    const u16* __restrict__ qf, const u16* __restrict__ kf,
    const u32* __restrict__ bitR, const u32* __restrict__ bitF,
    const void* __restrict__ mR, const void* __restrict__ mF,
    const int* __restrict__ flag,
    void* __restrict__ outp, float* __restrict__ partial) {

  __shared__ u16 s[2][4][8192];

  const int tid = threadIdx.x;
  const int lane = tid & 63, wid = tid >> 6;
  const int bx = blockIdx.x, by = blockIdx.y;
  const int rowBase = by * 128, colBase = bx * 128;

  const u16* base0 = qr + (size_t)rowBase * K_D;
  const u16* base1 = kr + (size_t)colBase * K_D;
  const u16* base2 = qf + (size_t)rowBase * K_D;
  const u16* base3 = kf + (size_t)colBase * K_D;

  f32x4 accR[4][2] = {}, accF[4][2] = {};

  auto STAGE = [&](int b, int k0) {
    const u16* bases[4] = {base0, base1, base2, base3};
#pragma unroll
    for (int t = 0; t < 4; ++t)
#pragma unroll
      for (int j = 0; j < 2; ++j) {
        int cid = j * 512 + tid;
        int row = cid >> 3;
        int k16 = (cid & 7) ^ (row & 7);
        gload_lds16(bases[t] + (size_t)row * K_D + k0 + k16 * 8,
                    &s[b][t][(j * 512 + wid * 64) * 8]);
      }
  };

  STAGE(0, 0);
  __syncthreads();

  const int waveM = wid >> 2, waveN = wid & 3;
  const int lrow = lane & 15, lk = lane >> 4;

  int cur = 0;
  for (int it = 0; it < 8; ++it) {
    if (it < 7) STAGE(cur ^ 1, (it + 1) * 64);
#pragma unroll
    for (int kk = 0; kk < 2; ++kk) {
      int k16 = kk * 4 + lk;
      f16x8 aR[4], aF[4], bR[2], bF[2];
#pragma unroll
      for (int mb = 0; mb < 4; ++mb) {
        int r = waveM * 64 + mb * 16 + lrow;
        int off = r * 64 + ((k16 ^ (r & 7)) << 3);
        aR[mb] = *(const f16x8*)&s[cur][0][off];
        aF[mb] = *(const f16x8*)&s[cur][2][off];
      }
#pragma unroll
      for (int nb = 0; nb < 2; ++nb) {
        int c = waveN * 32 + nb * 16 + lrow;
        int off = c * 64 + ((k16 ^ (c & 7)) << 3);
        bR[nb] = *(const f16x8*)&s[cur][1][off];
        bF[nb] = *(const f16x8*)&s[cur][3][off];
      }
#pragma unroll
      for (int mb = 0; mb < 4; ++mb)
#pragma unroll
        for (int nb = 0; nb < 2; ++nb) {
          accR[mb][nb] = __builtin_amdgcn_mfma_f32_16x16x32_f16(aR[mb], bR[nb], accR[mb][nb], 0, 0, 0);
          accF[mb][nb] = __builtin_amdgcn_mfma_f32_16x16x32_f16(aF[mb], bF[nb], accF[mb][nb], 0, 0, 0);
        }
    }
    __syncthreads();
    cur ^= 1;
  }

  const float scale = 0.04419417382415922f;
  const int mode = USEBITS ? 0 : *flag;
  u16*   vt16 = (u16*)&s[0][0][0];
  float* vt32 = (float*)&s[0][0][0];

#pragma unroll
  for (int mb = 0; mb < 4; ++mb)
#pragma unroll
    for (int rr = 0; rr < 4; ++rr) {
      int growl = waveM * 64 + mb * 16 + lk * 4 + rr;
      int grow = rowBase + growl;
      u32 wR = 0, wF = 0;
      if (USEBITS) {
        wR = bitR[(size_t)(bx * 4 + waveN) * K_N + grow];
        wF = bitF[(size_t)(bx * 4 + waveN) * K_N + grow];
      }
      float rs = 0.f;
#pragma unroll
      for (int nb = 0; nb < 2; ++nb) {
        int bitpos = nb * 16 + lrow;
        int gcoll = waveN * 32 + bitpos;
        bool m1, m2;
        if (USEBITS) {
          m1 = (wR >> bitpos) & 1u;
          m2 = (wF >> bitpos) & 1u;
        } else {
          size_t oi = (size_t)grow * K_N + colBase + gcoll;
          m1 = mask_at(mR, mode, oi);
          m2 = mask_at(mF, mode, oi);
        }
        float er = m1 ? 0.f : __expf(accR[mb][nb][rr] * scale);
        float ef = m2 ? 0.f : __expf(accF[mb][nb][rr] * scale);
        float v = er + 0.5f * ef;
        rs += v;
        if (F16OUT) vt16[growl * 136 + gcoll] = f2h(v);
        else        vt32[growl * 132 + gcoll] = v;
      }
      rs += __shfl_xor(rs, 1, 64);
      rs += __shfl_xor(rs, 2, 64);
      rs += __shfl_xor(rs, 4, 64);
      rs += __shfl_xor(rs, 8, 64);
      if (lrow == 0)
        partial[(size_t)grow * 256 + bx * 4 + waveN] = rs;
    }
  __syncthreads();

  if (F16OUT) {
    u16* out = (u16*)outp;
#pragma unroll
    for (int j = 0; j < 4; ++j) {
      int f = j * 512 + tid;
      int row = f >> 4, seg = f & 15;
      uint4 v = *(const uint4*)&vt16[row * 136 + seg * 8];
      *(uint4*)&out[(size_t)(rowBase + row) * K_N + colBase + seg * 8] = v;
    }
  } else {
    float* out = (float*)outp;
#pragma unroll
    for (int j = 0; j < 8; ++j) {
      int f = j * 512 + tid;
      int row = f >> 5, seg = f & 31;
      float4 v = *(const float4*)&vt32[row * 132 + seg * 4];
      *(float4*)&out[(size_t)(rowBase + row) * K_N + colBase + seg * 4] = v;
    }
  }
}

// ---------------------------------------------------------------------------
template <int STRIDE>
__global__ void k_rowsum(const float* __restrict__ partial, float* __restrict__ inv) {
  int r = blockIdx.x * 256 + threadIdx.x;
  const float4* p = (const float4*)(partial + (size_t)r * STRIDE);
  float s = 0.f;
#pragma unroll 8
  for (int j = 0; j < STRIDE / 4; j++) {
    float4 v = p[j];
    s += v.x + v.y + v.z + v.w;
  }
  inv[r] = 1.0f / s;
}

// fallback in-place fp32 norm
__global__ void k_norm_b(float* __restrict__ attn, const float* __restrict__ inv) {
  const size_t total = (size_t)K_N * K_N / 4;
  for (size_t i = (size_t)blockIdx.x * 256 + threadIdx.x; i < total;
       i += (size_t)gridDim.x * 256) {
    int row = (int)(i >> 11);
    float s = inv[row];
    float4 v = ((float4*)attn)[i];
    v.x *= s; v.y *= s; v.z *= s; v.w *= s;
    ((float4*)attn)[i] = v;
  }
}

// ---------------------------------------------------------------------------
// cntx: split-K, 4 blocks/CU, atomic accumulation into zeroed cntx,
// nontemporal attn stores. Block = (stripe 128 rows) x (ch 128 cols) x
// (ks K-range 2048); all 16 blocks of a stripe on one XCD.
// ---------------------------------------------------------------------------
__global__ __launch_bounds__(256, 4) void k_cntx6(
    const u16* __restrict__ sh, const u16* __restrict__ vT,
    const float* __restrict__ inv, float* __restrict__ cntx,
    float* __restrict__ attn) {
  __shared__ u16 sA[128 * 64], sB[128 * 64];
  f32x4 acc[4][4] = {};

  const int tid = threadIdx.x;
  int b = blockIdx.x + (blockIdx.y << 3);   // grid (8,128) -> b in [0,1024)
  int xcd = b & 7, j = b >> 3;              // j in [0,128)
  const int s  = xcd + 8 * (j >> 4);        // stripe 0..63
  const int u  = j & 15;
  const int ch = u >> 2;                    // col block 0..3
  const int ks = u & 3;                     // K split 0..3
  const int rowBase = s * 128, colBase = ch * 128;
  const int k0 = ks * 2048;

  gemm_core<0>(sh + (size_t)k0, K_N, vT + (size_t)k0, K_N,
               rowBase, colBase, 2048, sA, sB, acc);

  // atomic partial accumulation (inv applied per partial; sum distributes)
  const int lane = tid & 63;
  const int waveM = tid >> 7, waveN = (tid >> 6) & 1;
  const int lrow = lane & 15, lk = lane >> 4;
#pragma unroll
  for (int mb = 0; mb < 4; mb++)
#pragma unroll
    for (int rr = 0; rr < 4; rr++) {
      int grow = rowBase + waveM * 64 + mb * 16 + lk * 4 + rr;
      float iv = inv[grow];
#pragma unroll
      for (int nb = 0; nb < 4; nb++) {
        int gcol = colBase + waveN * 64 + nb * 16 + lrow;
        atomicAdd(&cntx[(size_t)grow * K_D + gcol], acc[mb][nb][rr] * iv);
      }
    }

  // attn normalize: rows [rowBase,+128), cols [ks*2048 + ch*512, +512)
  const int ac0 = ks * 2048 + ch * 512;
  const u16* src = sh + (size_t)rowBase * K_N + ac0;
  float* ad = attn + (size_t)rowBase * K_N + ac0;
  for (int i = tid; i < 128 * 64; i += 256) {   // 8-elem chunks
    int row = i >> 6, c8 = i & 63;
    float sc = inv[rowBase + row];
    uint4 v = *(const uint4*)&src[(size_t)row * K_N + c8 * 8];
    f32x4 o0, o1;
    o0.x = h2f(v.x & 0xFFFF) * sc; o0.y = h2f(v.x >> 16) * sc;
    o0.z = h2f(v.y & 0xFFFF) * sc; o0.w = h2f(v.y >> 16) * sc;
    o1.x = h2f(v.z & 0xFFFF) * sc; o1.y = h2f(v.z >> 16) * sc;
    o1.z = h2f(v.w & 0xFFFF) * sc; o1.w = h2f(v.w >> 16) * sc;
    float* d2 = ad + (size_t)row * K_N + c8 * 8;
    nt_store4(d2, o0);
    nt_store4(d2 + 4, o1);
  }
}

// ---------------------------------------------------------------------------
// Fallback cntx (reads fp32 attn), no attn emission.
// ---------------------------------------------------------------------------
template <int A_F32>
__global__ __launch_bounds__(256) void k_cntx(const void* __restrict__ Ap,
                                              const u16* __restrict__ vT,
                                              const float* __restrict__ inv,
                                              float* __restrict__ out) {
  __shared__ u16 sA[128 * 64], sB[128 * 64];
  f32x4 acc[4][4] = {};
  int b = blockIdx.x + blockIdx.y * 4;
  int c = b & 7, jj = b >> 3;
  int xb = jj & 3, yb = c + 8 * (jj >> 2);
  const int rowBase = yb * 128, colBase = xb * 128;
  gemm_core<A_F32>(Ap, K_N, vT, K_N, rowBase, colBase, K_N, sA, sB, acc);

  const int lane = threadIdx.x & 63;
  const int waveM = threadIdx.x >> 7, waveN = (threadIdx.x >> 6) & 1;
  const int lrow = lane & 15, lk = lane >> 4;
#pragma unroll
  for (int mb = 0; mb < 4; mb++)
#pragma unroll
    for (int r = 0; r < 4; r++) {
      int grow = rowBase + waveM * 64 + mb * 16 + lk * 4 + r;
      float iv = inv[grow];
#pragma unroll
      for (int nb = 0; nb < 4; nb++) {
        int gcol = colBase + waveN * 64 + nb * 16 + lrow;
        out[(size_t)grow * K_D + gcol] = acc[mb][nb][r] * iv;
      }
    }
}

// ---------------------------------------------------------------------------
extern "C" void kernel_launch(void* const* d_in, const int* in_sizes, int n_in,
                              void* d_out, int out_size, void* d_ws, size_t ws_size,
                              hipStream_t stream) {
  const float* x   = (const float*)d_in[0];
  const void*  mR  = d_in[1];
  const void*  mF  = d_in[2];
  const float* Wv  = (const float*)d_in[7];
  const float* bv  = (const float*)d_in[8];

  const size_t ND = (size_t)K_N * K_D;
  u16* xh = (u16*)d_ws;
  u16* qr = xh + ND;
  u16* kr = qr + ND;
  u16* qf = kr + ND;
  u16* kf = qf + ND;
  u16* vh = kf + ND;
  u16* vT = vh + ND;
  u16* wt = vT + ND;
  u32* bitR = (u32*)(wt + 5 * 262144);
  u32* bitF = bitR + (size_t)K_N * 256;
  u16* sh   = (u16*)(bitF + (size_t)K_N * 256);

  const size_t need_bits = (size_t)((char*)sh - (char*)d_ws) + 64;
  const size_t need_sh   = (size_t)((char*)sh - (char*)d_ws) + (size_t)K_N * K_N * 2;
  const bool have_bits = ws_size >= need_bits;
  const bool have_sh   = ws_size >= need_sh;

  float* cntx = (float*)d_out;
  float* attn = cntx + ND;
  float* partial = (float*)d_ws;                 // overlays xh (dead after proj)
  float* inv     = (float*)qr;                   // overlays qr (dead after scores)
  int* flag = have_bits ? (int*)sh : (int*)cntx;

  k_detect<<<1, 256, 0, stream>>>((const unsigned char*)mR, flag);
  if (have_bits)
    k_packmask2<<<dim3(64, 8), 256, 0, stream>>>(mR, mF, flag, bitR, bitF);

  k_cvt_x<<<4096, 256, 0, stream>>>(x, xh);
  k_transpose<1><<<dim3(8, 8), 256, 0, stream>>>((const void*)d_in[3], wt + 0 * 262144, 512, 512);
  k_transpose<1><<<dim3(8, 8), 256, 0, stream>>>((const void*)d_in[4], wt + 1 * 262144, 512, 512);
  k_transpose<1><<<dim3(8, 8), 256, 0, stream>>>((const void*)d_in[5], wt + 2 * 262144, 512, 512);
  k_transpose<1><<<dim3(8, 8), 256, 0, stream>>>((const void*)d_in[6], wt + 3 * 262144, 512, 512);
  k_transpose<1><<<dim3(8, 8), 256, 0, stream>>>(Wv,  wt + 4 * 262144, 512, 512);

  k_proj<<<dim3(4, 64, 5), 256, 0, stream>>>(xh, wt, qr, kr, qf, kf, vh, bv);
  k_transpose<0><<<dim3(8, 128), 256, 0, stream>>>(vh, vT, K_N, K_D);

  if (have_sh && have_bits) {
    k_scores2<<<dim3(64, 64), 256, 0, stream>>>(qr, kr, qf, kf, bitR, bitF, sh, partial);
    k_rowsum<128><<<32, 256, 0, stream>>>(partial, inv);
    k_zero<<<4096, 256, 0, stream>>>(cntx);
    k_cntx6<<<dim3(8, 128), 256, 0, stream>>>(sh, vT, inv, cntx, attn);
  } else if (have_bits) {
    k_scores8<0, 1><<<dim3(64, 64), 512, 0, stream>>>(qr, kr, qf, kf, bitR, bitF,
                                                      mR, mF, flag, attn, partial);
    k_rowsum<256><<<32, 256, 0, stream>>>(partial, inv);
    k_cntx<1><<<dim3(4, 64), 256, 0, stream>>>(attn, vT, inv, cntx);
    k_norm_b<<<8192, 256, 0, stream>>>(attn, inv);
  } else {
    k_scores8<0, 0><<<dim3(64, 64), 512, 0, stream>>>(qr, kr, qf, kf, nullptr, nullptr,
                                                      mR, mF, flag, attn, partial);
    k_rowsum<256><<<32, 256, 0, stream>>>(partial, inv);
    k_cntx<1><<<dim3(4, 64), 256, 0, stream>>>(attn, vT, inv, cntx);
    k_norm_b<<<8192, 256, 0, stream>>>(attn, inv);
  }
}

// Round 17
// 574.394 us; speedup vs baseline: 1.5309x; 1.0111x over previous
//
#include <hip/hip_runtime.h>

// ---------------------------------------------------------------------------
// SpatialAttention, N=8192, D=H=512, GAMMA=0.5
//   S = exp(maskR ? -inf : QrKr^T/sqrt(H)) + 0.5*exp(maskF ? -inf : QfKf^T/sqrt(H))
//   attn = S / rowsum(S);  cntx = attn @ (x Wv + bv)
// d_out = [cntx (N*D f32) | attn (N*N f32)]
//
// R17: dispatch-chain slimming (hot kernels untouched):
//  - k_cvt_x deleted; k_proj stages x (f32) directly via gemm_core<1>
//  - 5 weight transposes fused into one k_transpose_w (grid z=5)
//  - k_zero folded into k_packmask2 (zeroing overlaps mask streaming)
// ---------------------------------------------------------------------------

#define K_N 8192
#define K_D 512

typedef float  f32x4 __attribute__((ext_vector_type(4)));
typedef _Float16 f16x8 __attribute__((ext_vector_type(8)));
typedef unsigned short u16;
typedef unsigned int u32;

__device__ __forceinline__ u16 f2h(float f) {
  _Float16 h = (_Float16)f;
  return __builtin_bit_cast(u16, h);
}
__device__ __forceinline__ float h2f(u16 b) {
  return (float)__builtin_bit_cast(_Float16, b);
}

__device__ __forceinline__ void gload_lds16(const void* g, void* l) {
  __builtin_amdgcn_global_load_lds(
      (const __attribute__((address_space(1))) void*)g,
      (__attribute__((address_space(3))) void*)l, 16, 0, 0);
}

__device__ __forceinline__ void nt_store4(float* p, f32x4 v) {
  __builtin_nontemporal_store(v, (f32x4*)p);
}

// ---------------------------------------------------------------------------
// Mask dtype detector (1-byte bool vs 4-byte int/float).
// ---------------------------------------------------------------------------
__global__ void k_detect(const unsigned char* __restrict__ m, int* __restrict__ flag) {
  __shared__ int any;
  if (threadIdx.x == 0) any = 0;
  __syncthreads();
  int local = 0;
  for (int i = threadIdx.x; i < 65536; i += 256)
    local |= m[4 * i + 1];
  if (local) atomicOr(&any, 1);
  __syncthreads();
  if (threadIdx.x == 0) *flag = any ? 1 : 0;
}

__device__ __forceinline__ bool mask_at(const void* mask, int mode, size_t idx) {
  if (mode) return ((const unsigned char*)mask)[idx] != 0;
  return ((const int*)mask)[idx] != 0;
}

// ---------------------------------------------------------------------------
// pack 32 mask elements starting at (r, 32c) into one u32 (bit k = elem!=0)
// ---------------------------------------------------------------------------
__device__ __forceinline__ u32 pack_word(const void* m, int mode, int r, int c) {
  u32 out = 0;
  if (mode) {  // 1-byte elements: 32 B contiguous
    const uint4* p = (const uint4*)((const unsigned char*)m + (size_t)r * K_N + c * 32);
    uint4 a = p[0], b = p[1];
    u32 ws[8] = {a.x, a.y, a.z, a.w, b.x, b.y, b.z, b.w};
#pragma unroll
    for (int i = 0; i < 8; i++) {
      u32 v = ws[i];
      v |= v >> 4; v |= v >> 2; v |= v >> 1;
      v &= 0x01010101u;
      out |= (v & 1u) << (4 * i);
      out |= ((v >> 8) & 1u) << (4 * i + 1);
      out |= ((v >> 16) & 1u) << (4 * i + 2);
      out |= ((v >> 24) & 1u) << (4 * i + 3);
    }
  } else {     // 4-byte elements: 128 B contiguous
    const uint4* p = (const uint4*)((const int*)m + (size_t)r * K_N + c * 32);
#pragma unroll
    for (int i = 0; i < 8; i++) {
      uint4 v = p[i];
      out |= (v.x ? 1u : 0u) << (4 * i);
      out |= (v.y ? 1u : 0u) << (4 * i + 1);
      out |= (v.z ? 1u : 0u) << (4 * i + 2);
      out |= (v.w ? 1u : 0u) << (4 * i + 3);
    }
  }
  return out;
}

// ---------------------------------------------------------------------------
// packmask: LDS-transposed tiles; read input-major, write output-major.
// R17: also zeroes this block's cntx slice (overlapped with mask streaming).
// ---------------------------------------------------------------------------
__global__ __launch_bounds__(256) void k_packmask2(
    const void* __restrict__ mR, const void* __restrict__ mF,
    const int* __restrict__ flag,
    u32* __restrict__ bR, u32* __restrict__ bF,
    float* __restrict__ cntx) {
  __shared__ u32 sm[32][129];
  const int mode = *flag;
  const int tid = threadIdx.x;
  const int r0 = blockIdx.x * 128;
  const int c0 = blockIdx.y * 32;

  // zero this block's cntx slice: 512 blocks x 2048 float4 = 4M floats
  {
    float4* cz = (float4*)cntx;
    int bid = blockIdx.x + (blockIdx.y << 6);
#pragma unroll
    for (int i = 0; i < 8; ++i)
      cz[(size_t)bid * 2048 + i * 256 + tid] = make_float4(0.f, 0.f, 0.f, 0.f);
  }

#pragma unroll
  for (int t = 0; t < 2; ++t) {
    const void* m = t ? mF : mR;
    u32* dst = t ? bF : bR;
    if (t) __syncthreads();
#pragma unroll 4
    for (int i = 0; i < 16; ++i) {
      int idx = i * 256 + tid;
      int r = idx >> 5, c = idx & 31;
      sm[c][r] = pack_word(m, mode, r0 + r, c0 + c);
    }
    __syncthreads();
#pragma unroll 4
    for (int i = 0; i < 16; ++i) {
      int idx = i * 256 + tid;
      int c = idx >> 7, r = idx & 127;
      dst[(size_t)(c0 + c) * K_N + r0 + r] = sm[c][r];
    }
  }
}

// ---------------------------------------------------------------------------
// Fused weight transposes: z in [0,5) -> wt[z] = W_z^T (f32 -> fp16), 512x512
// ---------------------------------------------------------------------------
__global__ void k_transpose_w(const float* __restrict__ w0, const float* __restrict__ w1,
                              const float* __restrict__ w2, const float* __restrict__ w3,
                              const float* __restrict__ w4, u16* __restrict__ out) {
  __shared__ u16 sm[64][65];
  const float* srcs[5] = {w0, w1, w2, w3, w4};
  const float* in = srcs[blockIdx.z];
  u16* dst = out + (size_t)blockIdx.z * 262144;
  int c0 = blockIdx.x * 64, r0 = blockIdx.y * 64;
#pragma unroll
  for (int e = 0; e < 16; e++) {
    int idx = e * 256 + threadIdx.x;
    int i = idx >> 6, j = idx & 63;
    sm[i][j] = f2h(in[(size_t)(r0 + i) * 512 + c0 + j]);
  }
  __syncthreads();
#pragma unroll
  for (int e = 0; e < 16; e++) {
    int idx = e * 256 + threadIdx.x;
    int j = idx >> 6, i = idx & 63;
    dst[(size_t)(c0 + j) * 512 + r0 + i] = sm[i][j];
  }
}

// fp16 transpose for V (R x C -> C x R)
__global__ void k_transpose_v(const u16* __restrict__ in, u16* __restrict__ out,
                              int R, int C) {
  __shared__ u16 sm[64][65];
  int c0 = blockIdx.x * 64, r0 = blockIdx.y * 64;
#pragma unroll
  for (int e = 0; e < 16; e++) {
    int idx = e * 256 + threadIdx.x;
    int i = idx >> 6, j = idx & 63;
    sm[i][j] = in[(size_t)(r0 + i) * C + c0 + j];
  }
  __syncthreads();
#pragma unroll
  for (int e = 0; e < 16; e++) {
    int idx = e * 256 + threadIdx.x;
    int j = idx >> 6, i = idx & 63;
    out[(size_t)(c0 + j) * R + r0 + i] = sm[i][j];
  }
}

// ---------------------------------------------------------------------------
// Reg-staged 4-wave GEMM core: C(128x128) += A(128xK)*Bt^T
// ---------------------------------------------------------------------------
template <int A_F32>
__device__ __forceinline__ void gemm_core(const void* __restrict__ Ap, int lda,
                                          const u16* __restrict__ Bt, int ldb,
                                          int rowBase, int colBase, int K,
                                          u16* sA, u16* sB, f32x4 (&acc)[4][4]) {
  const int tid   = threadIdx.x;
  const int lane  = tid & 63;
  const int waveM = tid >> 7;
  const int waveN = (tid >> 6) & 1;
  const int lrow  = lane & 15;
  const int lk    = lane >> 4;

  for (int k0 = 0; k0 < K; k0 += 64) {
    __syncthreads();
#pragma unroll
    for (int g = 0; g < 4; g++) {
      int cid = g * 256 + tid;
      int row = cid >> 3;
      int pk  = cid & 7;
      int k16 = pk ^ (row & 7);
      if (A_F32) {
        const float* s = (const float*)Ap + (size_t)(rowBase + row) * lda + k0 + k16 * 8;
        float4 v0 = *(const float4*)s;
        float4 v1 = *(const float4*)(s + 4);
        ushort4 h0, h1;
        h0.x = f2h(v0.x); h0.y = f2h(v0.y); h0.z = f2h(v0.z); h0.w = f2h(v0.w);
        h1.x = f2h(v1.x); h1.y = f2h(v1.y); h1.z = f2h(v1.z); h1.w = f2h(v1.w);
        *(ushort4*)&sA[cid * 8]     = h0;
        *(ushort4*)&sA[cid * 8 + 4] = h1;
      } else {
        uint4 v = *(const uint4*)((const u16*)Ap + (size_t)(rowBase + row) * lda + k0 + k16 * 8);
        *(uint4*)&sA[cid * 8] = v;
      }
      uint4 w = *(const uint4*)(Bt + (size_t)(colBase + row) * ldb + k0 + k16 * 8);
      *(uint4*)&sB[cid * 8] = w;
    }
    __syncthreads();
#pragma unroll
    for (int kk = 0; kk < 2; kk++) {
      f16x8 af[4], bfv[4];
      int k16 = kk * 4 + lk;
#pragma unroll
      for (int mb = 0; mb < 4; mb++) {
        int r = waveM * 64 + mb * 16 + lrow;
        af[mb] = *(const f16x8*)&sA[r * 64 + ((k16 ^ (r & 7)) << 3)];
      }
#pragma unroll
      for (int nb = 0; nb < 4; nb++) {
        int c = waveN * 64 + nb * 16 + lrow;
        bfv[nb] = *(const f16x8*)&sB[c * 64 + ((k16 ^ (c & 7)) << 3)];
      }
#pragma unroll
      for (int mb = 0; mb < 4; mb++)
#pragma unroll
        for (int nb = 0; nb < 4; nb++)
          acc[mb][nb] = __builtin_amdgcn_mfma_f32_16x16x32_f16(af[mb], bfv[nb], acc[mb][nb], 0, 0, 0);
    }
  }
}

// ---------------------------------------------------------------------------
// Projections: z=0..3 -> Q_r,K_r,Q_f,K_f; z=4 -> V=x@Wv+bv (all fp16)
// R17: reads x (f32) directly via gemm_core<1> (cvt_x kernel deleted).
// ---------------------------------------------------------------------------
__global__ __launch_bounds__(256) void k_proj(const float* __restrict__ x,
                                              const u16* __restrict__ wt,
                                              u16* __restrict__ qr, u16* __restrict__ kr,
                                              u16* __restrict__ qf, u16* __restrict__ kf,
                                              u16* __restrict__ vh,
                                              const float* __restrict__ bv) {
  __shared__ u16 sA[128 * 64], sB[128 * 64];
  f32x4 acc[4][4] = {};
  const int z = blockIdx.z;
  const int rowBase = blockIdx.y * 128, colBase = blockIdx.x * 128;
  gemm_core<1>(x, K_D, wt + (size_t)z * 262144, K_D, rowBase, colBase, K_D, sA, sB, acc);

  u16* out = (z == 0) ? qr : (z == 1) ? kr : (z == 2) ? qf : (z == 3) ? kf : vh;
  const int lane = threadIdx.x & 63;
  const int waveM = threadIdx.x >> 7, waveN = (threadIdx.x >> 6) & 1;
  const int lrow = lane & 15, lk = lane >> 4;
#pragma unroll
  for (int mb = 0; mb < 4; mb++)
#pragma unroll
    for (int nb = 0; nb < 4; nb++)
#pragma unroll
      for (int r = 0; r < 4; r++) {
        int grow = rowBase + waveM * 64 + mb * 16 + lk * 4 + r;
        int gcol = colBase + waveN * 64 + nb * 16 + lrow;
        float v = acc[mb][nb][r];
        if (z == 4) v += bv[gcol];
        out[(size_t)grow * K_D + gcol] = f2h(v);
      }
}

// ---------------------------------------------------------------------------
// Main scores: 4 waves (256 thr), wave = 64x64, 64 KB dbuf, sequential R/F
// K-loops with cross-boundary prefetch, XCD swizzle, dual-bit-word epilogue,
// partial stride 128. launch_bounds(256,2): dual accumulators ~190 VGPR ->
// 2 blocks/CU register limit (R13 proved (256,4) spills catastrophically).
// ---------------------------------------------------------------------------
__global__ __launch_bounds__(256, 2) void k_scores2(
    const u16* __restrict__ qr, const u16* __restrict__ kr,
    const u16* __restrict__ qf, const u16* __restrict__ kf,
    const u32* __restrict__ bitR, const u32* __restrict__ bitF,
    u16* __restrict__ outp, float* __restrict__ partial) {

  __shared__ u16 s[2][2][8192];   // [dbuf][Q,K][128x64] = 64 KiB

  const int tid = threadIdx.x;
  const int lane = tid & 63, wid = tid >> 6;

  int b = blockIdx.x + (blockIdx.y << 6);
  int xcd = b & 7, j = b >> 3;            // j in [0,512)
  const int by = xcd * 8 + (j & 7);
  const int bx = j >> 3;
  const int rowBase = by * 128, colBase = bx * 128;

  const u16* qrB = qr + (size_t)rowBase * K_D;
  const u16* krB = kr + (size_t)colBase * K_D;
  const u16* qfB = qf + (size_t)rowBase * K_D;
  const u16* kfB = kf + (size_t)colBase * K_D;

  f32x4 accR[4][4] = {}, accF[4][4] = {};

  auto STAGE = [&](int buf, const u16* qb, const u16* kb, int k0) {
#pragma unroll
    for (int jj = 0; jj < 4; ++jj) {
      int cid = jj * 256 + tid;           // 16B chunk id, 0..1023
      int row = cid >> 3;
      int k16 = (cid & 7) ^ (row & 7);    // swizzled source -> linear LDS
      gload_lds16(qb + (size_t)row * K_D + k0 + k16 * 8,
                  &s[buf][0][(jj * 256 + wid * 64) * 8]);
      gload_lds16(kb + (size_t)row * K_D + k0 + k16 * 8,
                  &s[buf][1][(jj * 256 + wid * 64) * 8]);
    }
  };

  const int waveM = wid >> 1;         // 0..1 (64 rows)
  const int waveN = wid & 1;          // 0..1 (64 cols)
  const int lrow = lane & 15, lk = lane >> 4;

  auto COMPUTE = [&](f32x4 (&acc)[4][4], int cur) {
#pragma unroll
    for (int kk = 0; kk < 2; ++kk) {
      int k16 = kk * 4 + lk;
      f16x8 a[4], bb[4];
#pragma unroll
      for (int mb = 0; mb < 4; ++mb) {
        int r = waveM * 64 + mb * 16 + lrow;
        a[mb] = *(const f16x8*)&s[cur][0][r * 64 + ((k16 ^ (r & 7)) << 3)];
      }
#pragma unroll
      for (int nb = 0; nb < 4; ++nb) {
        int c = waveN * 64 + nb * 16 + lrow;
        bb[nb] = *(const f16x8*)&s[cur][1][c * 64 + ((k16 ^ (c & 7)) << 3)];
      }
#pragma unroll
      for (int mb = 0; mb < 4; ++mb)
#pragma unroll
        for (int nb = 0; nb < 4; ++nb)
          acc[mb][nb] = __builtin_amdgcn_mfma_f32_16x16x32_f16(a[mb], bb[nb], acc[mb][nb], 0, 0, 0);
    }
  };

  STAGE(0, qrB, krB, 0);
  __syncthreads();
  int cur = 0;
  for (int it = 0; it < 8; ++it) {        // real branch
    if (it < 7) STAGE(cur ^ 1, qrB, krB, (it + 1) * 64);
    else        STAGE(cur ^ 1, qfB, kfB, 0);
    COMPUTE(accR, cur);
    __syncthreads();
    cur ^= 1;
  }
  for (int it = 0; it < 8; ++it) {        // fake branch
    if (it < 7) STAGE(cur ^ 1, qfB, kfB, (it + 1) * 64);
    COMPUTE(accF, cur);
    __syncthreads();
    cur ^= 1;
  }

  // ---- epilogue: masked exp, rowsum partials, coalesced fp16 store ----
  const float scale = 0.04419417382415922f;   // 1/sqrt(512)
  u16* vt16 = (u16*)&s[0][0][0];              // [128][136] fp16 restage

#pragma unroll
  for (int mb = 0; mb < 4; ++mb)
#pragma unroll
    for (int rr = 0; rr < 4; ++rr) {
      int growl = waveM * 64 + mb * 16 + lk * 4 + rr;
      int grow = rowBase + growl;
      u32 wR0 = bitR[(size_t)(bx * 4 + waveN * 2 + 0) * K_N + grow];
      u32 wR1 = bitR[(size_t)(bx * 4 + waveN * 2 + 1) * K_N + grow];
      u32 wF0 = bitF[(size_t)(bx * 4 + waveN * 2 + 0) * K_N + grow];
      u32 wF1 = bitF[(size_t)(bx * 4 + waveN * 2 + 1) * K_N + grow];
      float rs = 0.f;
#pragma unroll
      for (int nb = 0; nb < 4; ++nb) {
        int cc = nb * 16 + lrow;            // 0..63 within wave cols
        int gcoll = waveN * 64 + cc;
        u32 wR = (cc >> 5) ? wR1 : wR0;
        u32 wF = (cc >> 5) ? wF1 : wF0;
        int bitpos = cc & 31;
        bool m1 = (wR >> bitpos) & 1u;
        bool m2 = (wF >> bitpos) & 1u;
        float er = m1 ? 0.f : __expf(accR[mb][nb][rr] * scale);
        float ef = m2 ? 0.f : __expf(accF[mb][nb][rr] * scale);
        float v = er + 0.5f * ef;
        rs += v;
        vt16[growl * 136 + gcoll] = f2h(v);
      }
      rs += __shfl_xor(rs, 1, 64);
      rs += __shfl_xor(rs, 2, 64);
      rs += __shfl_xor(rs, 4, 64);
      rs += __shfl_xor(rs, 8, 64);
      if (lrow == 0)
        partial[(size_t)grow * 128 + bx * 2 + waveN] = rs;
    }
  __syncthreads();

#pragma unroll
  for (int jj = 0; jj < 8; ++jj) {
    int f = jj * 256 + tid;             // 16B unit in 128x128 fp16 tile
    int row = f >> 4, seg = f & 15;
    uint4 v = *(const uint4*)&vt16[row * 136 + seg * 8];
    *(uint4*)&outp[(size_t)(rowBase + row) * K_N + colBase + seg * 8] = v;
  }
}

// ---------------------------------------------------------------------------
// Fallback scores: 8-wave, 128 KB LDS, raw masks or bits (partial stride 256).
// ---------------------------------------------------------------------------
template <int F16OUT, int USEBITS>
__global__ __launch_bounds__(512, 2) void k_scores8(
    const u16* __restrict__ qr, const u16* __restrict__ kr,
    const u16* __restrict__ qf, const u16* __restrict__ kf,
    const u32* __restrict__ bitR, const u32* __restrict__ bitF,
    const void* __restrict__ mR, const void* __restrict__ mF,
    const int* __restrict__ flag,
    void* __restrict__ outp, float* __restrict__ partial) {

  __shared__ u16 s[2][4][8192];

  const int tid = threadIdx.x;
  const int lane = tid & 63, wid = tid >> 6;
  const int bx = blockIdx.x, by = blockIdx.y;
  const int rowBase = by * 128, colBase = bx * 128;

  const u16* base0 = qr + (size_t)rowBase * K_D;
  const u16* base1 = kr + (size_t)colBase * K_D;
  const u16* base2 = qf + (size_t)rowBase * K_D;
  const u16* base3 = kf + (size_t)colBase * K_D;

  f32x4 accR[4][2] = {}, accF[4][2] = {};

  auto STAGE = [&](int b, int k0) {
    const u16* bases[4] = {base0, base1, base2, base3};
#pragma unroll
    for (int t = 0; t < 4; ++t)
#pragma unroll
      for (int j = 0; j < 2; ++j) {
        int cid = j * 512 + tid;
        int row = cid >> 3;
        int k16 = (cid & 7) ^ (row & 7);
        gload_lds16(bases[t] + (size_t)row * K_D + k0 + k16 * 8,
                    &s[b][t][(j * 512 + wid * 64) * 8]);
      }
  };

  STAGE(0, 0);
  __syncthreads();

  const int waveM = wid >> 2, waveN = wid & 3;
  const int lrow = lane & 15, lk = lane >> 4;

  int cur = 0;
  for (int it = 0; it < 8; ++it) {
    if (it < 7) STAGE(cur ^ 1, (it + 1) * 64);
#pragma unroll
    for (int kk = 0; kk < 2; ++kk) {
      int k16 = kk * 4 + lk;
      f16x8 aR[4], aF[4], bR[2], bF[2];
#pragma unroll
      for (int mb = 0; mb < 4; ++mb) {
        int r = waveM * 64 + mb * 16 + lrow;
        int off = r * 64 + ((k16 ^ (r & 7)) << 3);
        aR[mb] = *(const f16x8*)&s[cur][0][off];
        aF[mb] = *(const f16x8*)&s[cur][2][off];
      }
#pragma unroll
      for (int nb = 0; nb < 2; ++nb) {
        int c = waveN * 32 + nb * 16 + lrow;
        int off = c * 64 + ((k16 ^ (c & 7)) << 3);
        bR[nb] = *(const f16x8*)&s[cur][1][off];
        bF[nb] = *(const f16x8*)&s[cur][3][off];
      }
#pragma unroll
      for (int mb = 0; mb < 4; ++mb)
#pragma unroll
        for (int nb = 0; nb < 2; ++nb) {
          accR[mb][nb] = __builtin_amdgcn_mfma_f32_16x16x32_f16(aR[mb], bR[nb], accR[mb][nb], 0, 0, 0);
          accF[mb][nb] = __builtin_amdgcn_mfma_f32_16x16x32_f16(aF[mb], bF[nb], accF[mb][nb], 0, 0, 0);
        }
    }
    __syncthreads();
    cur ^= 1;
  }

  const float scale = 0.04419417382415922f;
  const int mode = USEBITS ? 0 : *flag;
  u16*   vt16 = (u16*)&s[0][0][0];
  float* vt32 = (float*)&s[0][0][0];

#pragma unroll
  for (int mb = 0; mb < 4; ++mb)
#pragma unroll
    for (int rr = 0; rr < 4; ++rr) {
      int growl = waveM * 64 + mb * 16 + lk * 4 + rr;
      int grow = rowBase + growl;
      u32 wR = 0, wF = 0;
      if (USEBITS) {
        wR = bitR[(size_t)(bx * 4 + waveN) * K_N + grow];
        wF = bitF[(size_t)(bx * 4 + waveN) * K_N + grow];
      }
      float rs = 0.f;
#pragma unroll
      for (int nb = 0; nb < 2; ++nb) {
        int bitpos = nb * 16 + lrow;
        int gcoll = waveN * 32 + bitpos;
        bool m1, m2;
        if (USEBITS) {
          m1 = (wR >> bitpos) & 1u;
          m2 = (wF >> bitpos) & 1u;
        } else {
          size_t oi = (size_t)grow * K_N + colBase + gcoll;
          m1 = mask_at(mR, mode, oi);
          m2 = mask_at(mF, mode, oi);
        }
        float er = m1 ? 0.f : __expf(accR[mb][nb][rr] * scale);
        float ef = m2 ? 0.f : __expf(accF[mb][nb][rr] * scale);
        float v = er + 0.5f * ef;
        rs += v;
        if (F16OUT) vt16[growl * 136 + gcoll] = f2h(v);
        else        vt32[growl * 132 + gcoll] = v;
      }
      rs += __shfl_xor(rs, 1, 64);
      rs += __shfl_xor(rs, 2, 64);
      rs += __shfl_xor(rs, 4, 64);
      rs += __shfl_xor(rs, 8, 64);
      if (lrow == 0)
        partial[(size_t)grow * 256 + bx * 4 + waveN] = rs;
    }
  __syncthreads();

  if (F16OUT) {
    u16* out = (u16*)outp;
#pragma unroll
    for (int j = 0; j < 4; ++j) {
      int f = j * 512 + tid;
      int row = f >> 4, seg = f & 15;
      uint4 v = *(const uint4*)&vt16[row * 136 + seg * 8];
      *(uint4*)&out[(size_t)(rowBase + row) * K_N + colBase + seg * 8] = v;
    }
  } else {
    float* out = (float*)outp;
#pragma unroll
    for (int j = 0; j < 8; ++j) {
      int f = j * 512 + tid;
      int row = f >> 5, seg = f & 31;
      float4 v = *(const float4*)&vt32[row * 132 + seg * 4];
      *(float4*)&out[(size_t)(rowBase + row) * K_N + colBase + seg * 4] = v;
    }
  }
}

// ---------------------------------------------------------------------------
template <int STRIDE>
__global__ void k_rowsum(const float* __restrict__ partial, float* __restrict__ inv) {
  int r = blockIdx.x * 256 + threadIdx.x;
  const float4* p = (const float4*)(partial + (size_t)r * STRIDE);
  float s = 0.f;
#pragma unroll 8
  for (int j = 0; j < STRIDE / 4; j++) {
    float4 v = p[j];
    s += v.x + v.y + v.z + v.w;
  }
  inv[r] = 1.0f / s;
}

// fallback in-place fp32 norm
__global__ void k_norm_b(float* __restrict__ attn, const float* __restrict__ inv) {
  const size_t total = (size_t)K_N * K_N / 4;
  for (size_t i = (size_t)blockIdx.x * 256 + threadIdx.x; i < total;
       i += (size_t)gridDim.x * 256) {
    int row = (int)(i >> 11);
    float s = inv[row];
    float4 v = ((float4*)attn)[i];
    v.x *= s; v.y *= s; v.z *= s; v.w *= s;
    ((float4*)attn)[i] = v;
  }
}

// ---------------------------------------------------------------------------
// cntx: split-K, 4 blocks/CU, atomic accumulation into zeroed cntx,
// nontemporal attn stores. Block = (stripe 128 rows) x (ch 128 cols) x
// (ks K-range 2048); all 16 blocks of a stripe on one XCD.
// ---------------------------------------------------------------------------
__global__ __launch_bounds__(256, 4) void k_cntx6(
    const u16* __restrict__ sh, const u16* __restrict__ vT,
    const float* __restrict__ inv, float* __restrict__ cntx,
    float* __restrict__ attn) {
  __shared__ u16 sA[128 * 64], sB[128 * 64];
  f32x4 acc[4][4] = {};

  const int tid = threadIdx.x;
  int b = blockIdx.x + (blockIdx.y << 3);   // grid (8,128) -> b in [0,1024)
  int xcd = b & 7, j = b >> 3;              // j in [0,128)
  const int s  = xcd + 8 * (j >> 4);        // stripe 0..63
  const int u  = j & 15;
  const int ch = u >> 2;                    // col block 0..3
  const int ks = u & 3;                     // K split 0..3
  const int rowBase = s * 128, colBase = ch * 128;
  const int k0 = ks * 2048;

  gemm_core<0>(sh + (size_t)k0, K_N, vT + (size_t)k0, K_N,
               rowBase, colBase, 2048, sA, sB, acc);

  // atomic partial accumulation (inv applied per partial; sum distributes)
  const int lane = tid & 63;
  const int waveM = tid >> 7, waveN = (tid >> 6) & 1;
  const int lrow = lane & 15, lk = lane >> 4;
#pragma unroll
  for (int mb = 0; mb < 4; mb++)
#pragma unroll
    for (int rr = 0; rr < 4; rr++) {
      int grow = rowBase + waveM * 64 + mb * 16 + lk * 4 + rr;
      float iv = inv[grow];
#pragma unroll
      for (int nb = 0; nb < 4; nb++) {
        int gcol = colBase + waveN * 64 + nb * 16 + lrow;
        atomicAdd(&cntx[(size_t)grow * K_D + gcol], acc[mb][nb][rr] * iv);
      }
    }

  // attn normalize: rows [rowBase,+128), cols [ks*2048 + ch*512, +512)
  const int ac0 = ks * 2048 + ch * 512;
  const u16* src = sh + (size_t)rowBase * K_N + ac0;
  float* ad = attn + (size_t)rowBase * K_N + ac0;
  for (int i = tid; i < 128 * 64; i += 256) {   // 8-elem chunks
    int row = i >> 6, c8 = i & 63;
    float sc = inv[rowBase + row];
    uint4 v = *(const uint4*)&src[(size_t)row * K_N + c8 * 8];
    f32x4 o0, o1;
    o0.x = h2f(v.x & 0xFFFF) * sc; o0.y = h2f(v.x >> 16) * sc;
    o0.z = h2f(v.y & 0xFFFF) * sc; o0.w = h2f(v.y >> 16) * sc;
    o1.x = h2f(v.z & 0xFFFF) * sc; o1.y = h2f(v.z >> 16) * sc;
    o1.z = h2f(v.w & 0xFFFF) * sc; o1.w = h2f(v.w >> 16) * sc;
    float* d2 = ad + (size_t)row * K_N + c8 * 8;
    nt_store4(d2, o0);
    nt_store4(d2 + 4, o1);
  }
}

// ---------------------------------------------------------------------------
// Fallback cntx (reads fp32 attn), no attn emission.
// ---------------------------------------------------------------------------
template <int A_F32>
__global__ __launch_bounds__(256) void k_cntx(const void* __restrict__ Ap,
                                              const u16* __restrict__ vT,
                                              const float* __restrict__ inv,
                                              float* __restrict__ out) {
  __shared__ u16 sA[128 * 64], sB[128 * 64];
  f32x4 acc[4][4] = {};
  int b = blockIdx.x + blockIdx.y * 4;
  int c = b & 7, jj = b >> 3;
  int xb = jj & 3, yb = c + 8 * (jj >> 2);
  const int rowBase = yb * 128, colBase = xb * 128;
  gemm_core<A_F32>(Ap, K_N, vT, K_N, rowBase, colBase, K_N, sA, sB, acc);

  const int lane = threadIdx.x & 63;
  const int waveM = threadIdx.x >> 7, waveN = (threadIdx.x >> 6) & 1;
  const int lrow = lane & 15, lk = lane >> 4;
#pragma unroll
  for (int mb = 0; mb < 4; mb++)
#pragma unroll
    for (int r = 0; r < 4; r++) {
      int grow = rowBase + waveM * 64 + mb * 16 + lk * 4 + r;
      float iv = inv[grow];
#pragma unroll
      for (int nb = 0; nb < 4; nb++) {
        int gcol = colBase + waveN * 64 + nb * 16 + lrow;
        out[(size_t)grow * K_D + gcol] = acc[mb][nb][r] * iv;
      }
    }
}

// ---------------------------------------------------------------------------
extern "C" void kernel_launch(void* const* d_in, const int* in_sizes, int n_in,
                              void* d_out, int out_size, void* d_ws, size_t ws_size,
                              hipStream_t stream) {
  const float* x   = (const float*)d_in[0];
  const void*  mR  = d_in[1];
  const void*  mF  = d_in[2];
  const float* Wv  = (const float*)d_in[7];
  const float* bv  = (const float*)d_in[8];

  const size_t ND = (size_t)K_N * K_D;
  u16* xh = (u16*)d_ws;                    // region kept for partial overlay
  u16* qr = xh + ND;
  u16* kr = qr + ND;
  u16* qf = kr + ND;
  u16* kf = qf + ND;
  u16* vh = kf + ND;
  u16* vT = vh + ND;
  u16* wt = vT + ND;
  u32* bitR = (u32*)(wt + 5 * 262144);
  u32* bitF = bitR + (size_t)K_N * 256;
  u16* sh   = (u16*)(bitF + (size_t)K_N * 256);

  const size_t need_bits = (size_t)((char*)sh - (char*)d_ws) + 64;
  const size_t need_sh   = (size_t)((char*)sh - (char*)d_ws) + (size_t)K_N * K_N * 2;
  const bool have_bits = ws_size >= need_bits;
  const bool have_sh   = ws_size >= need_sh;

  float* cntx = (float*)d_out;
  float* attn = cntx + ND;
  float* partial = (float*)d_ws;                 // overlays xh (scratch)
  float* inv     = (float*)qr;                   // overlays qr (dead after scores)
  int* flag = have_bits ? (int*)sh : (int*)cntx;

  k_detect<<<1, 256, 0, stream>>>((const unsigned char*)mR, flag);
  if (have_bits)
    k_packmask2<<<dim3(64, 8), 256, 0, stream>>>(mR, mF, flag, bitR, bitF, cntx);

  k_transpose_w<<<dim3(8, 8, 5), 256, 0, stream>>>(
      (const float*)d_in[3], (const float*)d_in[4], (const float*)d_in[5],
      (const float*)d_in[6], Wv, wt);

  k_proj<<<dim3(4, 64, 5), 256, 0, stream>>>(x, wt, qr, kr, qf, kf, vh, bv);
  k_transpose_v<<<dim3(8, 128), 256, 0, stream>>>(vh, vT, K_N, K_D);

  if (have_sh && have_bits) {
    k_scores2<<<dim3(64, 64), 256, 0, stream>>>(qr, kr, qf, kf, bitR, bitF, sh, partial);
    k_rowsum<128><<<32, 256, 0, stream>>>(partial, inv);
    k_cntx6<<<dim3(8, 128), 256, 0, stream>>>(sh, vT, inv, cntx, attn);
  } else if (have_bits) {
    k_scores8<0, 1><<<dim3(64, 64), 512, 0, stream>>>(qr, kr, qf, kf, bitR, bitF,
                                                      mR, mF, flag, attn, partial);
    k_rowsum<256><<<32, 256, 0, stream>>>(partial, inv);
    k_cntx<1><<<dim3(4, 64), 256, 0, stream>>>(attn, vT, inv, cntx);
    k_norm_b<<<8192, 256, 0, stream>>>(attn, inv);
  } else {
    k_scores8<0, 0><<<dim3(64, 64), 512, 0, stream>>>(qr, kr, qf, kf, nullptr, nullptr,
                                                      mR, mF, flag, attn, partial);
    k_rowsum<256><<<32, 256, 0, stream>>>(partial, inv);
    k_cntx<1><<<dim3(4, 64), 256, 0, stream>>>(attn, vT, inv, cntx);
    k_norm_b<<<8192, 256, 0, stream>>>(attn, inv);
  }
}